// Round 7
// baseline (109.241 us; speedup 1.0000x reference)
//
#include <hip/hip_runtime.h>

#define NUM_EMB 1024
#define EDIM 64
#define HW 4096      // 64*64 spatial
#define CHW 262144   // 64 ch * 4096
#define NPOS 65536   // 16 * 4096 positions
#define NOUT 4194304 // output elements (excl. loss scalar)
#define PPB 32       // positions per block
#define XP 72        // LDS x-tile pitch in shorts (rows 144 B, 16B-aligned)

typedef __attribute__((ext_vector_type(8))) short short8;   // 8 bf16 = 4 VGPRs
typedef __attribute__((ext_vector_type(4))) float f32x4;

__device__ inline short f32_to_bf16_rne(float f) {
    unsigned u = __float_as_uint(f);
    unsigned r = (u + 0x7fffu + ((u >> 16) & 1u)) >> 16;
    return (short)r;
}
__device__ inline float bf16s_to_f32(short s) {
    return __uint_as_float(((unsigned)(unsigned short)s) << 16);
}

// Prep: codebook -> bf16(-e) swizzled B-fragments + biased half-norms + zero
// loss. Negated codes let MFMA produce score = h - x.e directly (acc init h).
// B-frag (16x16x32): lane=(n&15)|(quad<<4) holds B[n][chunk*32+quad*8+j], j=0..7.
__global__ void vq_prep_kernel(const float* __restrict__ emb,
                               short* __restrict__ bsw,
                               float* __restrict__ hnb,
                               float* __restrict__ loss_out) {
    const int gid = blockIdx.x * 256 + threadIdx.x;   // 0..16383
    if (gid == 0) *loss_out = 0.0f;
    const int k  = gid >> 4;          // code id
    const int c0 = (gid & 15) * 4;    // channel group base
    float4 v = *(const float4*)(emb + k * EDIM + c0);
    float s = v.x * v.x + v.y * v.y + v.z * v.z + v.w * v.w;
#pragma unroll
    for (int m = 1; m < 16; m <<= 1) s += __shfl_xor(s, m, 64);
    if (c0 == 0) hnb[k] = 0.5f * s + 0.25f;           // bias -> scores positive

    const int T = k >> 4, nl = k & 15;
    const int chunk = c0 >> 5, quad = (c0 >> 3) & 3, j = c0 & 7;
    const int lane  = nl | (quad << 4);
    union { short s4[4]; uint2 u2; } pk;
    pk.s4[0] = f32_to_bf16_rne(-v.x);                 // NEGATED
    pk.s4[1] = f32_to_bf16_rne(-v.y);
    pk.s4[2] = f32_to_bf16_rne(-v.z);
    pk.s4[3] = f32_to_bf16_rne(-v.w);
    *(uint2*)(bsw + ((T * 2 + chunk) * 64 + lane) * 8 + j) = pk.u2;
}

// Main: block = 32 positions, 4 waves, 8 blocks/CU (32 waves/CU = full TLP).
// All waves hold the same 2 M-tiles; wave w scans codebook quarter w.
// Packed-uint argmin: u = (bits(score) & ~0x3FF) | code_id (scores biased
// positive -> uint order == float order; low bits = first-index tie-break).
__global__ __launch_bounds__(256, 8) void vq_mfma_kernel(
        const float* __restrict__ inp,
        const float* __restrict__ emb,
        const short* __restrict__ bsw,
        const float* __restrict__ hnb,
        float* __restrict__ out,
        float* __restrict__ loss_out) {
    __shared__ short    xs[PPB * XP];    // 4.5 KB: x tile, [pos][ch] bf16
    __shared__ unsigned s_red[4][32];
    __shared__ int      s_idx[PPB];
    __shared__ float    s_wsum[4];

    const int tid    = threadIdx.x;
    const int w      = tid >> 6;        // wave id = codebook quarter
    const int lane   = tid & 63;
    const int lanelo = lane & 15;
    const int quad   = lane >> 4;
    const int pb     = blockIdx.x * PPB;
    const int b      = pb >> 12;        // 32 | 4096 -> whole block same batch
    const int hw0    = pb & 4095;
    const float* xbase = inp + b * CHW + hw0;

    // ---- stage input tile: 512 float4 loads, coalesced 128B segments ----
#pragma unroll
    for (int g = 0; g < 2; ++g) {
        const int i  = tid + 256 * g;     // 0..511
        const int c  = i >> 3;            // channel
        const int p4 = i & 7;             // position quad
        float4 v = *(const float4*)(xbase + c * HW + p4 * 4);
        xs[(p4 * 4 + 0) * XP + c] = f32_to_bf16_rne(v.x);
        xs[(p4 * 4 + 1) * XP + c] = f32_to_bf16_rne(v.y);
        xs[(p4 * 4 + 2) * XP + c] = f32_to_bf16_rne(v.z);
        xs[(p4 * 4 + 3) * XP + c] = f32_to_bf16_rne(v.w);
    }
    __syncthreads();

    // ---- A fragments from LDS: 2 M-tiles x 2 K-chunks, ds_read_b128 ----
    short8 a[2][2];
#pragma unroll
    for (int t = 0; t < 2; ++t)
#pragma unroll
        for (int chunk = 0; chunk < 2; ++chunk)
            a[t][chunk] = *(const short8*)&xs[(t * 16 + lanelo) * XP + chunk * 32 + quad * 8];

    unsigned best[2][4];
#pragma unroll
    for (int t = 0; t < 2; ++t)
#pragma unroll
        for (int r = 0; r < 4; ++r) best[t][r] = 0xFFFFFFFFu;

    // ---- k-loop: 16 tiles of 16 codes (this wave's quarter) ----
    int kn = w * 256 + lanelo;
    const short* bp = bsw + (size_t)(w * 16) * 1024;  // 1024 shorts per tile
#pragma unroll 1
    for (int T = 0; T < 16; ++T) {
        const short8 b0 = *(const short8*)(bp + lane * 8);
        const short8 b1 = *(const short8*)(bp + 512 + lane * 8);
        const float  h  = hnb[kn];
        f32x4 acc[2];
#pragma unroll
        for (int t = 0; t < 2; ++t) acc[t] = (f32x4){h, h, h, h};
#pragma unroll
        for (int t = 0; t < 2; ++t) {
            acc[t] = __builtin_amdgcn_mfma_f32_16x16x32_bf16(a[t][0], b0, acc[t], 0, 0, 0);
            acc[t] = __builtin_amdgcn_mfma_f32_16x16x32_bf16(a[t][1], b1, acc[t], 0, 0, 0);
        }
#pragma unroll
        for (int t = 0; t < 2; ++t)
#pragma unroll
            for (int r = 0; r < 4; ++r) {
                unsigned u = (__float_as_uint(acc[t][r]) & ~1023u) | (unsigned)kn;
                if (u < best[t][r]) best[t][r] = u;
            }
        kn += 16;
        bp += 1024;
    }

    // ---- cross-lane min over the 16 codes (lanelo bits), stash per wave ----
#pragma unroll
    for (int t = 0; t < 2; ++t)
#pragma unroll
        for (int r = 0; r < 4; ++r) {
            unsigned v = best[t][r];
#pragma unroll
            for (int m = 1; m < 16; m <<= 1) {
                unsigned o = __shfl_xor(v, m, 64);
                if (o < v) v = o;
            }
            if (lanelo == 0)
                s_red[w][t * 16 + quad * 4 + r] = v;  // C/D row = quad*4+r
        }
    __syncthreads();

    if (tid < PPB) {                                  // merge 4 codebook quarters
        unsigned u0 = s_red[0][tid], u1 = s_red[1][tid];
        unsigned u2 = s_red[2][tid], u3 = s_red[3][tid];
        unsigned m01 = u0 < u1 ? u0 : u1;
        unsigned m23 = u2 < u3 ? u2 : u3;
        s_idx[tid] = (int)((m01 < m23 ? m01 : m23) & 1023u);
    }
    __syncthreads();

    // ---- epilogue: thread = (channel, 4 consecutive positions) ----
    float part = 0.0f;
    float* obase = out + b * CHW + hw0;
#pragma unroll
    for (int g = 0; g < 2; ++g) {
        const int i  = tid + 256 * g;     // 0..511
        const int c  = i >> 3;
        const int p0 = (i & 7) * 4;
        float4 qv;
        qv.x = emb[s_idx[p0 + 0] * EDIM + c];
        qv.y = emb[s_idx[p0 + 1] * EDIM + c];
        qv.z = emb[s_idx[p0 + 2] * EDIM + c];
        qv.w = emb[s_idx[p0 + 3] * EDIM + c];
        float d;
        d = qv.x - bf16s_to_f32(xs[(p0 + 0) * XP + c]); part = fmaf(d, d, part);
        d = qv.y - bf16s_to_f32(xs[(p0 + 1) * XP + c]); part = fmaf(d, d, part);
        d = qv.z - bf16s_to_f32(xs[(p0 + 2) * XP + c]); part = fmaf(d, d, part);
        d = qv.w - bf16s_to_f32(xs[(p0 + 3) * XP + c]); part = fmaf(d, d, part);
        *(float4*)(obase + c * HW + p0) = qv;
    }

#pragma unroll
    for (int off = 32; off > 0; off >>= 1)
        part += __shfl_down(part, off, 64);
    if (lane == 0) s_wsum[w] = part;
    __syncthreads();
    if (tid == 0) {
        float s = (s_wsum[0] + s_wsum[1]) + (s_wsum[2] + s_wsum[3]);
        atomicAdd(loss_out, s * (1.25f / (float)NOUT));
    }
}

extern "C" void kernel_launch(void* const* d_in, const int* in_sizes, int n_in,
                              void* d_out, int out_size, void* d_ws, size_t ws_size,
                              hipStream_t stream) {
    const float* inp = (const float*)d_in[0];    // [16,64,64,64] fp32
    const float* emb = (const float*)d_in[1];    // [1024,64] fp32
    float* out  = (float*)d_out;                 // 4194304 quantized + 1 loss
    float* loss = out + NOUT;

    short* bsw = (short*)d_ws;                           // 128 KiB bf16 -e swizzled
    float* hnb = (float*)((char*)d_ws + 131072);         // 4 KiB biased half-norms

    vq_prep_kernel<<<64, 256, 0, stream>>>(emb, bsw, hnb, loss);
    vq_mfma_kernel<<<NPOS / PPB, 256, 0, stream>>>(inp, emb, bsw, hnb, out, loss);
}

// Round 8
// 100.119 us; speedup vs baseline: 1.0911x; 1.0911x over previous
//
#include <hip/hip_runtime.h>

#define NUM_EMB 1024
#define EDIM 64
#define HW 4096      // 64*64 spatial
#define CHW 262144   // 64 ch * 4096
#define NPOS 65536   // 16 * 4096 positions
#define NOUT 4194304 // output elements (excl. loss scalar)
#define PPB 128      // positions per block (4 waves x 32)

typedef __attribute__((ext_vector_type(8))) short short8;   // 8 bf16 = 4 VGPRs
typedef __attribute__((ext_vector_type(4))) float f32x4;

__device__ inline short f32_to_bf16_rne(float f) {
    unsigned u = __float_as_uint(f);
    unsigned r = (u + 0x7fffu + ((u >> 16) & 1u)) >> 16;
    return (short)r;
}

// Prep: codebook -> bf16(-e) swizzled B-fragments + biased half-norms + zero
// loss. Negated codes let MFMA produce score = h - x.e directly (acc init h).
// B-frag (16x16x32): lane=(n&15)|(quad<<4) holds B[n][chunk*32+quad*8+j], j=0..7.
__global__ void vq_prep_kernel(const float* __restrict__ emb,
                               short* __restrict__ bsw,
                               float* __restrict__ hnb,
                               float* __restrict__ loss_out) {
    const int gid = blockIdx.x * 256 + threadIdx.x;   // 0..16383
    if (gid == 0) *loss_out = 0.0f;
    const int k  = gid >> 4;          // code id
    const int c0 = (gid & 15) * 4;    // channel group base
    float4 v = *(const float4*)(emb + k * EDIM + c0);
    float s = v.x * v.x + v.y * v.y + v.z * v.z + v.w * v.w;
#pragma unroll
    for (int m = 1; m < 16; m <<= 1) s += __shfl_xor(s, m, 64);
    if (c0 == 0) hnb[k] = 0.5f * s + 0.25f;           // bias -> scores positive

    const int T = k >> 4, nl = k & 15;
    const int chunk = c0 >> 5, quad = (c0 >> 3) & 3, j = c0 & 7;
    const int lane  = nl | (quad << 4);
    union { short s4[4]; uint2 u2; } pk;
    pk.s4[0] = f32_to_bf16_rne(-v.x);                 // NEGATED
    pk.s4[1] = f32_to_bf16_rne(-v.y);
    pk.s4[2] = f32_to_bf16_rne(-v.z);
    pk.s4[3] = f32_to_bf16_rne(-v.w);
    *(uint2*)(bsw + ((T * 2 + chunk) * 64 + lane) * 8 + j) = pk.u2;
}

// Main: block = 128 positions, 4 waves; each wave owns its own 32 positions
// (2 M-tiles) and scans the FULL codebook out of LDS. The 128 KB swizzled
// codebook is staged into a 64 KB LDS buffer in two phases (coalesced uint4
// loads + ds_write_b128); the k-loop does only ds_read_b128 + MFMA + min —
// no per-iteration global traffic except 16 hnb dwords. 2 blocks/CU.
// Packed-uint argmin: u = (bits(score) & ~0x3FF) | code_id (scores biased
// positive -> uint order == float order; low bits = first-index tie-break).
__global__ __launch_bounds__(256) void vq_mfma_kernel(
        const float* __restrict__ inp,
        const float* __restrict__ emb,
        const short* __restrict__ bsw,
        const float* __restrict__ hnb,
        float* __restrict__ out,
        float* __restrict__ loss_out) {
    __shared__ __align__(16) short lsb[32768];   // 64 KB: half-codebook buffer
    // s_idx / s_wsum alias lsb after the k-loop (barrier-separated reuse).
    int*   s_idx  = (int*)lsb;                   // [128]
    float* s_wsum = (float*)(lsb + 256);         // [4]

    const int tid    = threadIdx.x;
    const int w      = tid >> 6;        // wave id: owns positions w*32..w*32+31
    const int lane   = tid & 63;
    const int lanelo = lane & 15;
    const int quad   = lane >> 4;
    const int pb     = blockIdx.x * PPB;
    const int b      = pb >> 12;        // 128 | 4096 -> block within one image
    const int hw0    = pb & 4095;

    // ---- A fragments (this wave's 32 positions): 2 M-tiles x 2 K-chunks ----
    // A[m=lane&15][k=quad*8+j]; direct strided global loads (one-time).
    short8 a[2][2];
#pragma unroll
    for (int t = 0; t < 2; ++t) {
        const int p = pb + w * 32 + t * 16 + lanelo;
        const float* xp = inp + (p >> 12) * CHW + (p & 4095);
#pragma unroll
        for (int chunk = 0; chunk < 2; ++chunk)
#pragma unroll
            for (int j = 0; j < 8; ++j) {
                int c = chunk * 32 + quad * 8 + j;
                a[t][chunk][j] = f32_to_bf16_rne(xp[c * HW]);
            }
    }

    unsigned best[2][4];
#pragma unroll
    for (int t = 0; t < 2; ++t)
#pragma unroll
        for (int r = 0; r < 4; ++r) best[t][r] = 0xFFFFFFFFu;

    // ---- k-loop: 2 phases x (stage 512 codes into LDS, scan 32 tiles) ----
#pragma unroll 1
    for (int phase = 0; phase < 2; ++phase) {
        const uint4* src = (const uint4*)bsw + phase * 4096;  // 64 KB half
        uint4* dst = (uint4*)lsb;
#pragma unroll
        for (int g = 0; g < 16; ++g)
            dst[tid + 256 * g] = src[tid + 256 * g];
        __syncthreads();

        int kn = phase * 512 + lanelo;
#pragma unroll 2
        for (int T = 0; T < 32; ++T) {
            const short8 b0 = *(const short8*)(lsb + T * 1024 + lane * 8);
            const short8 b1 = *(const short8*)(lsb + T * 1024 + 512 + lane * 8);
            const float  h  = hnb[kn];
            f32x4 acc[2];
#pragma unroll
            for (int t = 0; t < 2; ++t) acc[t] = (f32x4){h, h, h, h};
#pragma unroll
            for (int t = 0; t < 2; ++t) {
                acc[t] = __builtin_amdgcn_mfma_f32_16x16x32_bf16(a[t][0], b0, acc[t], 0, 0, 0);
                acc[t] = __builtin_amdgcn_mfma_f32_16x16x32_bf16(a[t][1], b1, acc[t], 0, 0, 0);
            }
#pragma unroll
            for (int t = 0; t < 2; ++t)
#pragma unroll
                for (int r = 0; r < 4; ++r) {
                    unsigned u = (__float_as_uint(acc[t][r]) & ~1023u) | (unsigned)kn;
                    if (u < best[t][r]) best[t][r] = u;
                }
            kn += 16;
        }
        __syncthreads();   // all waves done reading before restage / idx reuse
    }

    // ---- cross-lane min over the 16 codes (lanelo bits) -> final idx ----
#pragma unroll
    for (int t = 0; t < 2; ++t)
#pragma unroll
        for (int r = 0; r < 4; ++r) {
            unsigned v = best[t][r];
#pragma unroll
            for (int m = 1; m < 16; m <<= 1) {
                unsigned o = __shfl_xor(v, m, 64);
                if (o < v) v = o;
            }
            if (lanelo == 0)   // position row = quad*4+r (C/D layout)
                s_idx[w * 32 + t * 16 + quad * 4 + r] = (int)(v & 1023u);
        }
    __syncthreads();

    // ---- epilogue: thread = (channel, 4 consecutive positions) ----
    // exact fp32 emb gather, float4 x re-read (L2-hot), dwordx4 store, loss.
    float part = 0.0f;
    const float* xb = inp + b * CHW + hw0;
    float* ob = out + b * CHW + hw0;
#pragma unroll
    for (int g = 0; g < 8; ++g) {
        const int i  = tid + 256 * g;     // 0..2047
        const int c  = i >> 5;            // channel 0..63
        const int p0 = (i & 31) * 4;      // position group
        int4 kq = *(const int4*)&s_idx[p0];
        float4 qv;
        qv.x = emb[kq.x * EDIM + c];
        qv.y = emb[kq.y * EDIM + c];
        qv.z = emb[kq.z * EDIM + c];
        qv.w = emb[kq.w * EDIM + c];
        float4 xv = *(const float4*)(xb + c * HW + p0);
        float d;
        d = qv.x - xv.x; part = fmaf(d, d, part);
        d = qv.y - xv.y; part = fmaf(d, d, part);
        d = qv.z - xv.z; part = fmaf(d, d, part);
        d = qv.w - xv.w; part = fmaf(d, d, part);
        *(float4*)(ob + c * HW + p0) = qv;
    }

#pragma unroll
    for (int off = 32; off > 0; off >>= 1)
        part += __shfl_down(part, off, 64);
    __syncthreads();                      // lsb reads done; reuse as wsum
    if (lane == 0) s_wsum[w] = part;
    __syncthreads();
    if (tid == 0) {
        float s = (s_wsum[0] + s_wsum[1]) + (s_wsum[2] + s_wsum[3]);
        atomicAdd(loss_out, s * (1.25f / (float)NOUT));
    }
}

extern "C" void kernel_launch(void* const* d_in, const int* in_sizes, int n_in,
                              void* d_out, int out_size, void* d_ws, size_t ws_size,
                              hipStream_t stream) {
    const float* inp = (const float*)d_in[0];    // [16,64,64,64] fp32
    const float* emb = (const float*)d_in[1];    // [1024,64] fp32
    float* out  = (float*)d_out;                 // 4194304 quantized + 1 loss
    float* loss = out + NOUT;

    short* bsw = (short*)d_ws;                           // 128 KiB bf16 -e swizzled
    float* hnb = (float*)((char*)d_ws + 131072);         // 4 KiB biased half-norms

    vq_prep_kernel<<<64, 256, 0, stream>>>(emb, bsw, hnb, loss);
    vq_mfma_kernel<<<NPOS / PPB, 256, 0, stream>>>(inp, emb, bsw, hnb, out, loss);
}

// Round 9
// 95.458 us; speedup vs baseline: 1.1444x; 1.0488x over previous
//
#include <hip/hip_runtime.h>

#define NUM_EMB 1024
#define EDIM 64
#define HW 4096      // 64*64 spatial
#define CHW 262144   // 64 ch * 4096
#define NPOS 65536   // 16 * 4096 positions
#define NOUT 4194304 // output elements (excl. loss scalar)
#define PPB 64       // positions per block (4 waves x 16)

typedef __attribute__((ext_vector_type(8))) short short8;   // 8 bf16 = 4 VGPRs
typedef __attribute__((ext_vector_type(4))) float f32x4;

__device__ inline short f32_to_bf16_rne(float f) {
    unsigned u = __float_as_uint(f);
    unsigned r = (u + 0x7fffu + ((u >> 16) & 1u)) >> 16;
    return (short)r;
}

// Prep: codebook -> bf16(-e) swizzled B-fragments + biased half-norms + zero
// loss. Negated codes let MFMA produce score = h - x.e directly (acc init h).
// B-frag (16x16x32): lane=(n&15)|(quad<<4) holds B[n][chunk*32+quad*8+j], j=0..7.
__global__ void vq_prep_kernel(const float* __restrict__ emb,
                               short* __restrict__ bsw,
                               float* __restrict__ hnb,
                               float* __restrict__ loss_out) {
    const int gid = blockIdx.x * 256 + threadIdx.x;   // 0..16383
    if (gid == 0) *loss_out = 0.0f;
    const int k  = gid >> 4;          // code id
    const int c0 = (gid & 15) * 4;    // channel group base
    float4 v = *(const float4*)(emb + k * EDIM + c0);
    float s = v.x * v.x + v.y * v.y + v.z * v.z + v.w * v.w;
#pragma unroll
    for (int m = 1; m < 16; m <<= 1) s += __shfl_xor(s, m, 64);
    if (c0 == 0) hnb[k] = 0.5f * s + 0.25f;           // bias -> scores positive

    const int T = k >> 4, nl = k & 15;
    const int chunk = c0 >> 5, quad = (c0 >> 3) & 3, j = c0 & 7;
    const int lane  = nl | (quad << 4);
    union { short s4[4]; uint2 u2; } pk;
    pk.s4[0] = f32_to_bf16_rne(-v.x);                 // NEGATED
    pk.s4[1] = f32_to_bf16_rne(-v.y);
    pk.s4[2] = f32_to_bf16_rne(-v.z);
    pk.s4[3] = f32_to_bf16_rne(-v.w);
    *(uint2*)(bsw + ((T * 2 + chunk) * 64 + lane) * 8 + j) = pk.u2;
}

// Main: block = 64 positions, 4 waves; each wave owns 16 positions (1 M-tile)
// and scans the FULL codebook. Codebook streamed through LDS in 4 phases of
// 32 KB; half-norms staged to LDS once. The k-loop touches NO global memory:
// ds_read_b128 x2 + ds_read_b32(h) + 2 MFMA + packed-uint min. ~36.5 KB LDS
// -> 4 blocks/CU = 16 waves/CU; grid 1024 = fully co-resident.
// Packed-uint argmin: u = (bits(score) & ~0x3FF) | code_id (scores biased
// positive -> uint order == float order; low bits = first-index tie-break).
__global__ __launch_bounds__(256, 4) void vq_mfma_kernel(
        const float* __restrict__ inp,
        const float* __restrict__ emb,
        const short* __restrict__ bsw,
        const float* __restrict__ hnb,
        float* __restrict__ out,
        float* __restrict__ loss_out) {
    __shared__ __align__(16) short lsb[16384];   // 32 KB: quarter-codebook
    __shared__ __align__(16) float hl[1024];     // 4 KB: biased half-norms
    __shared__ int   s_idx[PPB];
    __shared__ float s_wsum[4];

    const int tid    = threadIdx.x;
    const int w      = tid >> 6;        // wave id: owns positions w*16..w*16+15
    const int lane   = tid & 63;
    const int lanelo = lane & 15;
    const int quad   = lane >> 4;
    const int pb     = blockIdx.x * PPB;
    const int b      = pb >> 12;        // 64 | 4096 -> block within one image
    const int hw0    = pb & 4095;

    // ---- stage all 1024 half-norms to LDS (once) ----
    *(float4*)&hl[tid * 4] = *(const float4*)&hnb[tid * 4];

    // ---- A fragments (this wave's 16 positions): 1 M-tile x 2 K-chunks ----
    // A[m=lane&15][k=quad*8+j]; strided global loads (one-time).
    short8 a[2];
    {
        const int p = pb + w * 16 + lanelo;
        const float* xp = inp + (p >> 12) * CHW + (p & 4095);
#pragma unroll
        for (int chunk = 0; chunk < 2; ++chunk)
#pragma unroll
            for (int j = 0; j < 8; ++j) {
                int c = chunk * 32 + quad * 8 + j;
                a[chunk][j] = f32_to_bf16_rne(xp[c * HW]);
            }
    }

    unsigned best[4];
#pragma unroll
    for (int r = 0; r < 4; ++r) best[r] = 0xFFFFFFFFu;

    // ---- k-loop: 4 phases x (stage 256 codes to LDS, scan 16 tiles) ----
#pragma unroll 1
    for (int phase = 0; phase < 4; ++phase) {
        const uint4* src = (const uint4*)bsw + phase * 2048;  // 32 KB quarter
        uint4* dst = (uint4*)lsb;
#pragma unroll
        for (int g = 0; g < 8; ++g)
            dst[tid + 256 * g] = src[tid + 256 * g];
        __syncthreads();

        int kn = phase * 256 + lanelo;
#pragma unroll 2
        for (int T = 0; T < 16; ++T) {
            const short8 b0 = *(const short8*)(lsb + T * 1024 + lane * 8);
            const short8 b1 = *(const short8*)(lsb + T * 1024 + 512 + lane * 8);
            const float  h  = hl[kn];
            f32x4 acc = {h, h, h, h};
            acc = __builtin_amdgcn_mfma_f32_16x16x32_bf16(a[0], b0, acc, 0, 0, 0);
            acc = __builtin_amdgcn_mfma_f32_16x16x32_bf16(a[1], b1, acc, 0, 0, 0);
#pragma unroll
            for (int r = 0; r < 4; ++r) {
                unsigned u = (__float_as_uint(acc[r]) & ~1023u) | (unsigned)kn;
                if (u < best[r]) best[r] = u;
            }
            kn += 16;
        }
        __syncthreads();   // drain readers before next phase restage
    }

    // ---- cross-lane min over the 16 codes (lanelo bits) -> final idx ----
#pragma unroll
    for (int r = 0; r < 4; ++r) {
        unsigned v = best[r];
#pragma unroll
        for (int m = 1; m < 16; m <<= 1) {
            unsigned o = __shfl_xor(v, m, 64);
            if (o < v) v = o;
        }
        if (lanelo == 0)   // position row = quad*4+r (C/D layout)
            s_idx[w * 16 + quad * 4 + r] = (int)(v & 1023u);
    }
    __syncthreads();

    // ---- epilogue: thread = (channel, 4 consecutive positions) ----
    // exact fp32 emb gather (L2-hot), float4 x re-read, dwordx4 store, loss.
    float part = 0.0f;
    const float* xb = inp + b * CHW + hw0;
    float* ob = out + b * CHW + hw0;
#pragma unroll
    for (int g = 0; g < 4; ++g) {
        const int i  = tid + 256 * g;     // 0..1023
        const int c  = i >> 4;            // channel 0..63
        const int p0 = (i & 15) * 4;      // position group
        int4 kq = *(const int4*)&s_idx[p0];
        float4 qv;
        qv.x = emb[kq.x * EDIM + c];
        qv.y = emb[kq.y * EDIM + c];
        qv.z = emb[kq.z * EDIM + c];
        qv.w = emb[kq.w * EDIM + c];
        float4 xv = *(const float4*)(xb + c * HW + p0);
        float d;
        d = qv.x - xv.x; part = fmaf(d, d, part);
        d = qv.y - xv.y; part = fmaf(d, d, part);
        d = qv.z - xv.z; part = fmaf(d, d, part);
        d = qv.w - xv.w; part = fmaf(d, d, part);
        *(float4*)(ob + c * HW + p0) = qv;
    }

#pragma unroll
    for (int off = 32; off > 0; off >>= 1)
        part += __shfl_down(part, off, 64);
    if (lane == 0) s_wsum[w] = part;
    __syncthreads();
    if (tid == 0) {
        float s = (s_wsum[0] + s_wsum[1]) + (s_wsum[2] + s_wsum[3]);
        atomicAdd(loss_out, s * (1.25f / (float)NOUT));
    }
}

extern "C" void kernel_launch(void* const* d_in, const int* in_sizes, int n_in,
                              void* d_out, int out_size, void* d_ws, size_t ws_size,
                              hipStream_t stream) {
    const float* inp = (const float*)d_in[0];    // [16,64,64,64] fp32
    const float* emb = (const float*)d_in[1];    // [1024,64] fp32
    float* out  = (float*)d_out;                 // 4194304 quantized + 1 loss
    float* loss = out + NOUT;

    short* bsw = (short*)d_ws;                           // 128 KiB bf16 -e swizzled
    float* hnb = (float*)((char*)d_ws + 131072);         // 4 KiB biased half-norms

    vq_prep_kernel<<<64, 256, 0, stream>>>(emb, bsw, hnb, loss);
    vq_mfma_kernel<<<NPOS / PPB, 256, 0, stream>>>(inp, emb, bsw, hnb, out, loss);
}